// Round 4
// baseline (398.580 us; speedup 1.0000x reference)
//
#include <hip/hip_runtime.h>
#include <stdint.h>

#define T_SEQ 4096
#define CEMB 768
#define HS 64
#define GRIDN 512u

typedef __attribute__((ext_vector_type(8))) short bf16x8;
typedef __attribute__((ext_vector_type(16))) float f32x16;
typedef __attribute__((ext_vector_type(4))) unsigned int u32x4;

__device__ __forceinline__ short bfru(float f) {   // round-half-up to bf16 (2 ops)
    uint32_t u = __builtin_bit_cast(uint32_t, f);
    return (short)((u + 0x8000u) >> 16);
}
// pack two f32 -> (bf16,bf16) dword, RNE
__device__ __forceinline__ uint32_t cvtpk_bf16(float lo, float hi) {
    uint32_t r;
    asm("v_cvt_pk_bf16_f32 %0, %1, %2" : "=v"(r) : "v"(lo), "v"(hi));
    return r;
}

// 768^-0.5 * log2(e): fold attention scale AND exp->exp2 conversion into Q
#define QSCALE (0.036084391824351615f * 1.4426950408889634f)

// Device-scope grid barrier: all GRIDN blocks co-resident (512 blocks, 2/CU by
// launch_bounds(256,2) + 37.9KB LDS). Release-add publishes this block's writes
// (L2 writeback), acquire-load invalidates stale cross-XCD lines.
__device__ __forceinline__ void gridbar(unsigned* c) {
    __syncthreads();
    if (threadIdx.x == 0) {
        __hip_atomic_fetch_add(c, 1u, __ATOMIC_RELEASE, __HIP_MEMORY_SCOPE_AGENT);
        while (__hip_atomic_load(c, __ATOMIC_ACQUIRE, __HIP_MEMORY_SCOPE_AGENT) < GRIDN)
            __builtin_amdgcn_s_sleep(2);
    }
    __syncthreads();
}

// =================== single persistent kernel: prep | qkv | attn | combine ==========
__global__ __launch_bounds__(256, 2) void fused(
        const float* __restrict__ x,
        const float* __restrict__ Wq, const float* __restrict__ bq,
        const float* __restrict__ Wk, const float* __restrict__ bk,
        const float* __restrict__ Wv, const float* __restrict__ bv,
        short* __restrict__ qo, short* __restrict__ ko, short* __restrict__ vto,
        short* __restrict__ wtf, float* __restrict__ Op, float* __restrict__ lp,
        unsigned* bars, const int ks, float* __restrict__ outf) {
    __shared__ __align__(16) char smem[37888];   // union: qkv S[2][4608]s | attn K/V/Lred

    const int tid  = threadIdx.x;
    const int bid  = blockIdx.x;
    const int wave = tid >> 6, lane = tid & 63;
    const int l31  = lane & 31, lhi = lane >> 5;

    // ---------------- phase 0: prep wtf (blocks 0..287) ----------------
    if (bid < 288) {
        const int p = bid;                 // ct*48 + kq
        const int jp = wave;               // 0..3
        const int kq = p % 48, ct = p / 48;
        const int k = kq * 16 + lhi * 8 + jp * 2;
        const int nn = ct * 32 + l31;
        const float* W = nn < 64 ? Wq : (nn < 128 ? Wk : Wv);
        const int col = nn & 63;
        uint32_t lo = (uint16_t)bfru(W[k * 64 + col]);
        uint32_t hi = (uint16_t)bfru(W[(k + 1) * 64 + col]);
        *(uint32_t*)&wtf[(p * 64 + lane) * 8 + jp * 2] = lo | (hi << 16);
    }
    gridbar(bars + 0);

    // ---------------- phase 1: fused QKV projection ----------------
    {
        short* S0 = (short*)smem;          // [64*72]
        short* S1 = (short*)(smem + 9216);
        const int rg   = wave & 1;
        const int ctb  = (wave >> 1) * 3;
        const int rowbase = bid * 64;

        f32x16 acc[3];
        #pragma unroll
        for (int c = 0; c < 3; ++c) {
            const int ct = ctb + c, nn = ct * 32 + l31;
            const float bb = nn < 64 ? bq[nn] : (nn < 128 ? bk[nn - 64] : bv[nn - 128]);
            #pragma unroll
            for (int r = 0; r < 16; ++r) acc[c][r] = bb;
        }

        const int sr = tid >> 2, sseg = (tid & 3) * 16;
        const float* xrow = x + (long)(rowbase + sr) * CEMB + sseg;
        const short* wfb = wtf + (long)ctb * 48 * 512 + lane * 8;

        float4 RA0, RA1, RA2, RA3;
        float4 RB0, RB1, RB2, RB3;
        {   // prologue: tile0 -> RA -> S0; issue tile1 -> RB
            const float4* s0 = (const float4*)xrow;
            RA0 = s0[0]; RA1 = s0[1]; RA2 = s0[2]; RA3 = s0[3];
            const float4* s1 = (const float4*)(xrow + 64);
            RB0 = s1[0]; RB1 = s1[1]; RB2 = s1[2]; RB3 = s1[3];
            bf16x8 w0, w1;
            w0[0]=bfru(RA0.x); w0[1]=bfru(RA0.y); w0[2]=bfru(RA0.z); w0[3]=bfru(RA0.w);
            w0[4]=bfru(RA1.x); w0[5]=bfru(RA1.y); w0[6]=bfru(RA1.z); w0[7]=bfru(RA1.w);
            w1[0]=bfru(RA2.x); w1[1]=bfru(RA2.y); w1[2]=bfru(RA2.z); w1[3]=bfru(RA2.w);
            w1[4]=bfru(RA3.x); w1[5]=bfru(RA3.y); w1[6]=bfru(RA3.z); w1[7]=bfru(RA3.w);
            *(bf16x8*)&S0[sr * 72 + sseg]     = w0;
            *(bf16x8*)&S0[sr * 72 + sseg + 8] = w1;
        }
        __syncthreads();

        #pragma unroll
        for (int kt = 0; kt < 12; ++kt) {
            const int cur = kt & 1;
            short* Sc = cur ? S1 : S0;
            short* Sn = cur ? S0 : S1;
            bf16x8 wfr[12];
            #pragma unroll
            for (int kc = 0; kc < 4; ++kc)
                #pragma unroll
                for (int c = 0; c < 3; ++c)
                    wfr[kc * 3 + c] = *(const bf16x8*)(wfb + ((c * 48 + kt * 4 + kc) << 9));
            if (kt + 2 < 12) {
                const float4* sn = (const float4*)(xrow + (kt + 2) * 64);
                if (cur == 0) { RA0 = sn[0]; RA1 = sn[1]; RA2 = sn[2]; RA3 = sn[3]; }
                else          { RB0 = sn[0]; RB1 = sn[1]; RB2 = sn[2]; RB3 = sn[3]; }
            }
            #pragma unroll
            for (int kc = 0; kc < 4; ++kc) {
                bf16x8 af = *(const bf16x8*)&Sc[(rg * 32 + l31) * 72 + kc * 16 + lhi * 8];
                acc[0] = __builtin_amdgcn_mfma_f32_32x32x16_bf16(af, wfr[kc * 3 + 0], acc[0], 0, 0, 0);
                acc[1] = __builtin_amdgcn_mfma_f32_32x32x16_bf16(af, wfr[kc * 3 + 1], acc[1], 0, 0, 0);
                acc[2] = __builtin_amdgcn_mfma_f32_32x32x16_bf16(af, wfr[kc * 3 + 2], acc[2], 0, 0, 0);
            }
            if (kt + 1 < 12) {
                bf16x8 w0, w1;
                if (cur == 0) {
                    w0[0]=bfru(RB0.x); w0[1]=bfru(RB0.y); w0[2]=bfru(RB0.z); w0[3]=bfru(RB0.w);
                    w0[4]=bfru(RB1.x); w0[5]=bfru(RB1.y); w0[6]=bfru(RB1.z); w0[7]=bfru(RB1.w);
                    w1[0]=bfru(RB2.x); w1[1]=bfru(RB2.y); w1[2]=bfru(RB2.z); w1[3]=bfru(RB2.w);
                    w1[4]=bfru(RB3.x); w1[5]=bfru(RB3.y); w1[6]=bfru(RB3.z); w1[7]=bfru(RB3.w);
                } else {
                    w0[0]=bfru(RA0.x); w0[1]=bfru(RA0.y); w0[2]=bfru(RA0.z); w0[3]=bfru(RA0.w);
                    w0[4]=bfru(RA1.x); w0[5]=bfru(RA1.y); w0[6]=bfru(RA1.z); w0[7]=bfru(RA1.w);
                    w1[0]=bfru(RA2.x); w1[1]=bfru(RA2.y); w1[2]=bfru(RA2.z); w1[3]=bfru(RA2.w);
                    w1[4]=bfru(RA3.x); w1[5]=bfru(RA3.y); w1[6]=bfru(RA3.z); w1[7]=bfru(RA3.w);
                }
                *(bf16x8*)&Sn[sr * 72 + sseg]     = w0;
                *(bf16x8*)&Sn[sr * 72 + sseg + 8] = w1;
            }
            __syncthreads();
        }

        #pragma unroll
        for (int c = 0; c < 3; ++c) {
            const int ct = ctb + c;
            if (ct < 2) {
                #pragma unroll
                for (int r = 0; r < 16; ++r) {
                    const int row = rg * 32 + (r & 3) + 8 * (r >> 2) + 4 * lhi;
                    qo[(long)(rowbase + row) * HS + ct * 32 + l31] = bfru(acc[c][r] * QSCALE);
                }
            } else if (ct < 4) {
                #pragma unroll
                for (int r = 0; r < 16; ++r) {
                    const int row = rg * 32 + (r & 3) + 8 * (r >> 2) + 4 * lhi;
                    ko[(long)(rowbase + row) * HS + (ct - 2) * 32 + l31] = bfru(acc[c][r]);
                }
            } else {
                #pragma unroll
                for (int r = 0; r < 16; ++r) {
                    const int row = rg * 32 + (r & 3) + 8 * (r >> 2) + 4 * lhi;
                    S0[((ct - 4) * 32 + l31) * 72 + row] = bfru(acc[c][r]);   // V transpose staging
                }
            }
        }
        __syncthreads();
        if (tid < 128) {
            const int vcol = tid >> 1, hh = tid & 1;
            const int b = rowbase >> 12, t0 = rowbase & 4095;
            short* dst = vto + ((long)b * HS + vcol) * T_SEQ + t0 + hh * 32;
            #pragma unroll
            for (int i = 0; i < 4; ++i)
                *(bf16x8*)(dst + i * 8) = *(const bf16x8*)&S0[vcol * 72 + hh * 32 + i * 8];
        }
    }
    gridbar(bars + 1);

    // ---------------- phase 2: fused attention (key-split ks) ----------------
    if (bid < 128 * ks) {
        short* KldsB = (short*)smem;             // [2][4608]
        short* VldsB = (short*)(smem + 18432);   // [2][4608]
        float* LredB = (float*)(smem + 36864);   // [4][2][32]

        const int idx = bid;
        const int b = idx & 7, s = (idx >> 3) % ks, qt = idx / (8 * ks);
        const int slab = T_SEQ / ks, nkt = slab / 64;

        const short* qb = qo + ((long)b * T_SEQ + qt * 256 + wave * 64) * HS;
        const short* kb = ko + ((long)b * T_SEQ + s * slab) * HS;
        const short* vb = vto + (long)b * HS * T_SEQ + s * slab;

        bf16x8 qf[2][4];
        #pragma unroll
        for (int qs = 0; qs < 2; ++qs)
            #pragma unroll
            for (int kc = 0; kc < 4; ++kc)
                qf[qs][kc] = *(const bf16x8*)&qb[(qs * 32 + l31) * HS + kc * 16 + lhi * 8];

        f32x16 oacc[2][2] = {};          // [qs][ht]
        float lsum[2] = {0.f, 0.f};

        const int sr = tid >> 2, sc = (tid & 3) * 16;
        const short* kp = kb + sr * HS + sc;
        const short* vp = vb + sr * T_SEQ + sc;

        bf16x8 kr0 = *(const bf16x8*)kp, kr1 = *(const bf16x8*)(kp + 8);
        bf16x8 vr0 = *(const bf16x8*)vp, vr1 = *(const bf16x8*)(vp + 8);
        *(bf16x8*)&KldsB[sr * 72 + sc]     = kr0;
        *(bf16x8*)&KldsB[sr * 72 + sc + 8] = kr1;
        *(bf16x8*)&VldsB[sr * 72 + sc]     = vr0;
        *(bf16x8*)&VldsB[sr * 72 + sc + 8] = vr1;
        __syncthreads();

        for (int kt = 0; kt < nkt; ++kt) {
            const int cur = kt & 1;
            const bool pfe = (kt + 1 < nkt);
            if (pfe) {       // issue next-tile global loads early; consume after compute
                const short* kp2 = kp + (kt + 1) * (64 * HS);
                const short* vp2 = vp + (kt + 1) * 64;
                kr0 = *(const bf16x8*)kp2; kr1 = *(const bf16x8*)(kp2 + 8);
                vr0 = *(const bf16x8*)vp2; vr1 = *(const bf16x8*)(vp2 + 8);
            }
            const short* Kc = KldsB + cur * 4608;
            const short* Vc = VldsB + cur * 4608;
            #pragma unroll
            for (int ct = 0; ct < 2; ++ct) {
                const short* krow = &Kc[(ct * 32 + l31) * 72 + lhi * 8];
                bf16x8 kf0 = *(const bf16x8*)(krow);
                bf16x8 kf1 = *(const bf16x8*)(krow + 16);
                bf16x8 kf2 = *(const bf16x8*)(krow + 32);
                bf16x8 kf3 = *(const bf16x8*)(krow + 48);
                const short* vrow = &Vc[l31 * 72 + ct * 32 + lhi * 8];
                bf16x8 vf00 = *(const bf16x8*)(vrow);
                bf16x8 vf10 = *(const bf16x8*)(vrow + 16);
                bf16x8 vf01 = *(const bf16x8*)(vrow + 32 * 72);
                bf16x8 vf11 = *(const bf16x8*)(vrow + 32 * 72 + 16);
                #pragma unroll
                for (int qs = 0; qs < 2; ++qs) {
                    f32x16 z = {};
                    z = __builtin_amdgcn_mfma_f32_32x32x16_bf16(kf0, qf[qs][0], z, 0, 0, 0);
                    z = __builtin_amdgcn_mfma_f32_32x32x16_bf16(kf1, qf[qs][1], z, 0, 0, 0);
                    z = __builtin_amdgcn_mfma_f32_32x32x16_bf16(kf2, qf[qs][2], z, 0, 0, 0);
                    z = __builtin_amdgcn_mfma_f32_32x32x16_bf16(kf3, qf[qs][3], z, 0, 0, 0);
                    #pragma unroll
                    for (int r = 0; r < 16; ++r) z[r] = __builtin_amdgcn_exp2f(z[r]);
                    lsum[qs] += (((z[0]+z[1])+(z[2]+z[3])) + ((z[4]+z[5])+(z[6]+z[7])))
                              + (((z[8]+z[9])+(z[10]+z[11])) + ((z[12]+z[13])+(z[14]+z[15])));
                    uint32_t x0 = cvtpk_bf16(z[0],  z[1]),  y0 = cvtpk_bf16(z[4],  z[5]);
                    uint32_t x1 = cvtpk_bf16(z[2],  z[3]),  y1 = cvtpk_bf16(z[6],  z[7]);
                    uint32_t x2 = cvtpk_bf16(z[8],  z[9]),  y2 = cvtpk_bf16(z[12], z[13]);
                    uint32_t x3 = cvtpk_bf16(z[10], z[11]), y3 = cvtpk_bf16(z[14], z[15]);
                    asm("v_permlane32_swap_b32 %0, %1" : "+v"(x0), "+v"(y0));
                    asm("v_permlane32_swap_b32 %0, %1" : "+v"(x1), "+v"(y1));
                    asm("v_permlane32_swap_b32 %0, %1" : "+v"(x2), "+v"(y2));
                    asm("v_permlane32_swap_b32 %0, %1" : "+v"(x3), "+v"(y3));
                    u32x4 t0 = {x0, x1, y0, y1};
                    u32x4 t1 = {x2, x3, y2, y3};
                    bf16x8 pa0 = __builtin_bit_cast(bf16x8, t0);
                    bf16x8 pa1 = __builtin_bit_cast(bf16x8, t1);
                    oacc[qs][0] = __builtin_amdgcn_mfma_f32_32x32x16_bf16(pa0, vf00, oacc[qs][0], 0, 0, 0);
                    oacc[qs][1] = __builtin_amdgcn_mfma_f32_32x32x16_bf16(pa0, vf01, oacc[qs][1], 0, 0, 0);
                    oacc[qs][0] = __builtin_amdgcn_mfma_f32_32x32x16_bf16(pa1, vf10, oacc[qs][0], 0, 0, 0);
                    oacc[qs][1] = __builtin_amdgcn_mfma_f32_32x32x16_bf16(pa1, vf11, oacc[qs][1], 0, 0, 0);
                }
            }
            if (pfe) {
                short* Kn = KldsB + (cur ^ 1) * 4608;
                short* Vn = VldsB + (cur ^ 1) * 4608;
                *(bf16x8*)&Kn[sr * 72 + sc]     = kr0;
                *(bf16x8*)&Kn[sr * 72 + sc + 8] = kr1;
                *(bf16x8*)&Vn[sr * 72 + sc]     = vr0;
                *(bf16x8*)&Vn[sr * 72 + sc + 8] = vr1;
            }
            __syncthreads();
        }

        #pragma unroll
        for (int qs = 0; qs < 2; ++qs) lsum[qs] += __shfl_xor(lsum[qs], 32);

        const long rowg = (long)b * T_SEQ + qt * 256 + wave * 64;
        if (ks == 1) {
            if (lhi == 0) {
                LredB[(wave * 2 + 0) * 32 + l31] = lsum[0];
                LredB[(wave * 2 + 1) * 32 + l31] = lsum[1];
            }
            __syncthreads();
            float* ob = outf + rowg * HS;
            #pragma unroll
            for (int qs = 0; qs < 2; ++qs)
                #pragma unroll
                for (int ht = 0; ht < 2; ++ht)
                    #pragma unroll
                    for (int r = 0; r < 16; ++r) {
                        const int row = (r & 3) + 8 * (r >> 2) + 4 * lhi;
                        ob[(long)(qs * 32 + row) * HS + ht * 32 + l31] =
                            oacc[qs][ht][r] / LredB[(wave * 2 + qs) * 32 + row];
                    }
        } else {
            float* op = Op + ((long)s * 32768 + rowg) * HS;
            #pragma unroll
            for (int qs = 0; qs < 2; ++qs)
                #pragma unroll
                for (int ht = 0; ht < 2; ++ht)
                    #pragma unroll
                    for (int r = 0; r < 16; ++r) {
                        const int row = (r & 3) + 8 * (r >> 2) + 4 * lhi;
                        op[(qs * 32 + row) * HS + ht * 32 + l31] = oacc[qs][ht][r];
                    }
            if (lhi == 0) {
                lp[(long)s * 32768 + rowg + l31]      = lsum[0];
                lp[(long)s * 32768 + rowg + 32 + l31] = lsum[1];
            }
        }
    }

    // ---------------- phase 3: combine partials ----------------
    if (ks > 1) {
        gridbar(bars + 2);
        const float4* Opv = (const float4*)Op;
        float4* outv = (float4*)outf;
        #pragma unroll
        for (int i = 0; i < 4; ++i) {
            const int idx = (bid * 4 + i) * 256 + tid;   // 524288 items
            const int row = idx >> 4, h4 = idx & 15;
            float ox = 0.f, oy = 0.f, oz = 0.f, ow = 0.f, l = 0.f;
            for (int s2 = 0; s2 < ks; ++s2) {
                float4 t = Opv[(long)(s2 * 32768 + row) * 16 + h4];
                ox += t.x; oy += t.y; oz += t.z; ow += t.w;
                l += lp[s2 * 32768 + row];
            }
            const float inv = 1.0f / l;
            float4 o; o.x = ox * inv; o.y = oy * inv; o.z = oz * inv; o.w = ow * inv;
            outv[(long)row * 16 + h4] = o;
        }
    }
}

extern "C" void kernel_launch(void* const* d_in, const int* in_sizes, int n_in,
                              void* d_out, int out_size, void* d_ws, size_t ws_size,
                              hipStream_t stream) {
    const float* x  = (const float*)d_in[0];
    const float* Wq = (const float*)d_in[1];
    const float* bq = (const float*)d_in[2];
    const float* Wk = (const float*)d_in[3];
    const float* bk = (const float*)d_in[4];
    const float* Wv = (const float*)d_in[5];
    const float* bv = (const float*)d_in[6];

    char* ws = (char*)d_ws;
    short* qo  = (short*)(ws);                     // 4 MB
    short* ko  = (short*)(ws + (4u << 20));        // 4 MB
    short* vto = (short*)(ws + (8u << 20));        // 4 MB  [b][h][t]
    short* wtf = (short*)(ws + (12u << 20));       // 288 KB
    const size_t barOff = 12582912u + 294912u;     // 12877824: 3 barrier counters
    const size_t opOff  = barOff + 1024u;          // 12878848, 16B aligned
    float* Op = (float*)(ws + opOff);

    const size_t per_s = 8388608u + 131072u;       // O partial + l partial per split
    int ks = (ws_size >= opOff + 4 * per_s) ? 4
           : (ws_size >= opOff + 2 * per_s) ? 2 : 1;
    float* lp = (float*)(ws + opOff + (size_t)ks * 8388608u);
    unsigned* bars = (unsigned*)(ws + barOff);

    hipMemsetAsync(ws + barOff, 0, 1024, stream);  // zero barrier counters (poisoned)
    fused<<<GRIDN, 256, 0, stream>>>(x, Wq, bq, Wk, bk, Wv, bv,
                                     qo, ko, vto, wtf, Op, lp, bars, ks,
                                     (float*)d_out);
}

// Round 7
// 213.787 us; speedup vs baseline: 1.8644x; 1.8644x over previous
//
#include <hip/hip_runtime.h>
#include <stdint.h>

#define T_SEQ 4096
#define CEMB 768
#define HS 64

typedef __attribute__((ext_vector_type(8))) short bf16x8;
typedef __attribute__((ext_vector_type(16))) float f32x16;
typedef __attribute__((ext_vector_type(4))) unsigned int u32x4;

__device__ __forceinline__ short bfru(float f) {   // round-half-up to bf16 (2 ops)
    uint32_t u = __builtin_bit_cast(uint32_t, f);
    return (short)((u + 0x8000u) >> 16);
}
// pack two f32 -> (bf16,bf16) dword, RNE
__device__ __forceinline__ uint32_t cvtpk_bf16(float lo, float hi) {
    uint32_t r;
    asm("v_cvt_pk_bf16_f32 %0, %1, %2" : "=v"(r) : "v"(lo), "v"(hi));
    return r;
}

// 768^-0.5 * log2(e): fold attention scale AND exp->exp2 conversion into Q
#define QSCALE (0.036084391824351615f * 1.4426950408889634f)

// ---------------- prep: W -> bf16 MFMA B-fragment layout (coalesced) ----------------
__global__ __launch_bounds__(256) void prep_wt(const float* __restrict__ Wq,
                                               const float* __restrict__ Wk,
                                               const float* __restrict__ Wv,
                                               short* __restrict__ wtf) {
    const int p = blockIdx.x;                 // ct*48 + kq
    const int tid = threadIdx.x;
    const int lane = tid & 63, jp = tid >> 6;
    const int l31 = lane & 31, lhi = lane >> 5;
    const int kq = p % 48, ct = p / 48;
    const int k = kq * 16 + lhi * 8 + jp * 2;
    const int nn = ct * 32 + l31;
    const float* W = nn < 64 ? Wq : (nn < 128 ? Wk : Wv);
    const int col = nn & 63;
    uint32_t lo = (uint16_t)bfru(W[k * 64 + col]);
    uint32_t hi = (uint16_t)bfru(W[(k + 1) * 64 + col]);
    *(uint32_t*)&wtf[(p * 64 + lane) * 8 + jp * 2] = lo | (hi << 16);
}

// ---------------- fused QKV projection ----------------
// BM=32, grid 1024 -> 4 blocks/CU (16 waves/CU, was 8): occupancy fix for the
// latency-bound regime R2's counters showed (Occ 19.6%, MfmaUtil 5%). Per-wave:
// ct = wave (q0,q1,k0,k1); waves 0,1 also own ct 4,5 (v0,v1). Per-element MFMA
// order over (kt,kc) identical to the R3 kernel -> bit-identical qo/ko/vto.
__global__ __launch_bounds__(256, 4) void qkv_proj(const float* __restrict__ x,
        const float* __restrict__ bq, const float* __restrict__ bk, const float* __restrict__ bv,
        const short* __restrict__ wtf,
        short* __restrict__ qo, short* __restrict__ ko, short* __restrict__ vto) {
    __shared__ short S[2][32 * 72];

    const int tid  = threadIdx.x;
    const int wave = tid >> 6, lane = tid & 63;
    const int l31  = lane & 31, lhi = lane >> 5;
    const int rowbase = blockIdx.x * 32;
    const int ctA  = wave;              // 0..3: q0,q1,k0,k1
    const bool hasB = (wave < 2);
    const int ctB  = wave + 4;          // 4,5: v0,v1 (waves 0,1 only)

    f32x16 acc0, acc1;
    {
        const int nnA = ctA * 32 + l31;
        const float bA = nnA < 64 ? bq[nnA] : bk[nnA - 64];
        float bB = 0.f;
        if (hasB) bB = bv[(ctB - 4) * 32 + l31];
        #pragma unroll
        for (int r = 0; r < 16; ++r) { acc0[r] = bA; acc1[r] = bB; }
    }

    const int sr = tid >> 3, sseg = (tid & 7) * 8;   // 32 rows x 8 segs of 8 floats
    const float* xrow = x + (long)(rowbase + sr) * CEMB + sseg;
    const short* wfA = wtf + (long)ctA * 48 * 512 + lane * 8;
    const short* wfB = wtf + (long)ctB * 48 * 512 + lane * 8;

    float4 RA0, RA1, RB0, RB1;
    {   // prologue: tile0 -> RA -> S[0]; issue tile1 -> RB
        const float4* s0 = (const float4*)xrow;
        RA0 = s0[0]; RA1 = s0[1];
        const float4* s1 = (const float4*)(xrow + 64);
        RB0 = s1[0]; RB1 = s1[1];
        bf16x8 w;
        w[0]=bfru(RA0.x); w[1]=bfru(RA0.y); w[2]=bfru(RA0.z); w[3]=bfru(RA0.w);
        w[4]=bfru(RA1.x); w[5]=bfru(RA1.y); w[6]=bfru(RA1.z); w[7]=bfru(RA1.w);
        *(bf16x8*)&S[0][sr * 72 + sseg] = w;
    }
    __syncthreads();

    #pragma unroll
    for (int kt = 0; kt < 12; ++kt) {
        const int cur = kt & 1;
        bf16x8 wA[4], wB[4];
        #pragma unroll
        for (int kc = 0; kc < 4; ++kc)
            wA[kc] = *(const bf16x8*)(wfA + ((kt * 4 + kc) << 9));
        if (hasB) {
            #pragma unroll
            for (int kc = 0; kc < 4; ++kc)
                wB[kc] = *(const bf16x8*)(wfB + ((kt * 4 + kc) << 9));
        }
        if (kt + 2 < 12) {
            const float4* sn = (const float4*)(xrow + (kt + 2) * 64);
            if (cur == 0) { RA0 = sn[0]; RA1 = sn[1]; }
            else          { RB0 = sn[0]; RB1 = sn[1]; }
        }
        #pragma unroll
        for (int kc = 0; kc < 4; ++kc) {
            bf16x8 af = *(const bf16x8*)&S[cur][l31 * 72 + kc * 16 + lhi * 8];
            acc0 = __builtin_amdgcn_mfma_f32_32x32x16_bf16(af, wA[kc], acc0, 0, 0, 0);
            if (hasB)
                acc1 = __builtin_amdgcn_mfma_f32_32x32x16_bf16(af, wB[kc], acc1, 0, 0, 0);
        }
        if (kt + 1 < 12) {
            bf16x8 w;
            if (cur == 0) {
                w[0]=bfru(RB0.x); w[1]=bfru(RB0.y); w[2]=bfru(RB0.z); w[3]=bfru(RB0.w);
                w[4]=bfru(RB1.x); w[5]=bfru(RB1.y); w[6]=bfru(RB1.z); w[7]=bfru(RB1.w);
            } else {
                w[0]=bfru(RA0.x); w[1]=bfru(RA0.y); w[2]=bfru(RA0.z); w[3]=bfru(RA0.w);
                w[4]=bfru(RA1.x); w[5]=bfru(RA1.y); w[6]=bfru(RA1.z); w[7]=bfru(RA1.w);
            }
            *(bf16x8*)&S[cur ^ 1][sr * 72 + sseg] = w;
        }
        __syncthreads();
    }

    // epilogue.  C/D rows: row = (r&3)+8*(r>>2)+4*lhi (32-row tile, no row-group)
    if (ctA < 2) {
        #pragma unroll
        for (int r = 0; r < 16; ++r) {
            const int row = (r & 3) + 8 * (r >> 2) + 4 * lhi;
            qo[(long)(rowbase + row) * HS + ctA * 32 + l31] = bfru(acc0[r] * QSCALE);
        }
    } else {
        #pragma unroll
        for (int r = 0; r < 16; ++r) {
            const int row = (r & 3) + 8 * (r >> 2) + 4 * lhi;
            ko[(long)(rowbase + row) * HS + (ctA - 2) * 32 + l31] = bfru(acc0[r]);
        }
    }
    short* Sf = (short*)S;    // reuse as V^T staging [64 vcol][32 t] pitch 40 (5.1 KB)
    if (hasB) {
        #pragma unroll
        for (int r = 0; r < 16; ++r) {
            const int row = (r & 3) + 8 * (r >> 2) + 4 * lhi;
            Sf[((ctB - 4) * 32 + l31) * 40 + row] = bfru(acc1[r]);
        }
    }
    __syncthreads();
    {   // write v transposed: vto[b][h][t], coalesced along t
        const int vcol = tid >> 2, tseg = (tid & 3) * 8;
        const int b = rowbase >> 12, t0 = rowbase & 4095;
        *(bf16x8*)(vto + ((long)b * HS + vcol) * T_SEQ + t0 + tseg)
            = *(const bf16x8*)&Sf[vcol * 40 + tseg];
    }
}

// ---------------- fused attention (byte-identical to the 216.2us R3 kernel) --------
__global__ __launch_bounds__(256, 2) void attn(const short* __restrict__ qm,
        const short* __restrict__ km, const short* __restrict__ vtm,
        float* __restrict__ Op, float* __restrict__ lp, const int ks,
        float* __restrict__ outdirect) {
    __shared__ short Klds[2][64 * 72];   // [key][h]
    __shared__ short Vlds[2][64 * 72];   // [h][key]
    __shared__ float Lred[4][2][32];     // per-wave l broadcast (ks==1 path)

    const int tid  = threadIdx.x;
    const int wave = tid >> 6, lane = tid & 63;
    const int l31  = lane & 31, lhi = lane >> 5;
    const int idx  = blockIdx.x;
    const int b = idx & 7, s = (idx >> 3) % ks, qt = idx / (8 * ks);
    const int slab = T_SEQ / ks, nkt = slab / 64;

    const short* qb = qm + ((long)b * T_SEQ + qt * 256 + wave * 64) * HS;
    const short* kb = km + ((long)b * T_SEQ + s * slab) * HS;
    const short* vb = vtm + (long)b * HS * T_SEQ + s * slab;

    bf16x8 qf[2][4];
    #pragma unroll
    for (int qs = 0; qs < 2; ++qs)
        #pragma unroll
        for (int kc = 0; kc < 4; ++kc)
            qf[qs][kc] = *(const bf16x8*)&qb[(qs * 32 + l31) * HS + kc * 16 + lhi * 8];

    f32x16 oacc[2][2] = {};          // [qs][ht]
    float lsum[2] = {0.f, 0.f};

    const int sr = tid >> 2, sc = (tid & 3) * 16;
    const short* kp = kb + sr * HS + sc;
    const short* vp = vb + sr * T_SEQ + sc;

    bf16x8 kr0 = *(const bf16x8*)kp, kr1 = *(const bf16x8*)(kp + 8);
    bf16x8 vr0 = *(const bf16x8*)vp, vr1 = *(const bf16x8*)(vp + 8);
    *(bf16x8*)&Klds[0][sr * 72 + sc]     = kr0;
    *(bf16x8*)&Klds[0][sr * 72 + sc + 8] = kr1;
    *(bf16x8*)&Vlds[0][sr * 72 + sc]     = vr0;
    *(bf16x8*)&Vlds[0][sr * 72 + sc + 8] = vr1;
    __syncthreads();

    for (int kt = 0; kt < nkt; ++kt) {
        const int cur = kt & 1;
        const bool pfe = (kt + 1 < nkt);
        if (pfe) {       // issue next-tile global loads early; consume after compute
            const short* kp2 = kp + (kt + 1) * (64 * HS);
            const short* vp2 = vp + (kt + 1) * 64;
            kr0 = *(const bf16x8*)kp2; kr1 = *(const bf16x8*)(kp2 + 8);
            vr0 = *(const bf16x8*)vp2; vr1 = *(const bf16x8*)(vp2 + 8);
        }
        const short* Kc = Klds[cur];
        const short* Vc = Vlds[cur];
        #pragma unroll
        for (int ct = 0; ct < 2; ++ct) {
            const short* krow = &Kc[(ct * 32 + l31) * 72 + lhi * 8];
            bf16x8 kf0 = *(const bf16x8*)(krow);
            bf16x8 kf1 = *(const bf16x8*)(krow + 16);
            bf16x8 kf2 = *(const bf16x8*)(krow + 32);
            bf16x8 kf3 = *(const bf16x8*)(krow + 48);
            const short* vrow = &Vc[l31 * 72 + ct * 32 + lhi * 8];
            bf16x8 vf00 = *(const bf16x8*)(vrow);
            bf16x8 vf10 = *(const bf16x8*)(vrow + 16);
            bf16x8 vf01 = *(const bf16x8*)(vrow + 32 * 72);
            bf16x8 vf11 = *(const bf16x8*)(vrow + 32 * 72 + 16);
            #pragma unroll
            for (int qs = 0; qs < 2; ++qs) {
                f32x16 z = {};
                z = __builtin_amdgcn_mfma_f32_32x32x16_bf16(kf0, qf[qs][0], z, 0, 0, 0);
                z = __builtin_amdgcn_mfma_f32_32x32x16_bf16(kf1, qf[qs][1], z, 0, 0, 0);
                z = __builtin_amdgcn_mfma_f32_32x32x16_bf16(kf2, qf[qs][2], z, 0, 0, 0);
                z = __builtin_amdgcn_mfma_f32_32x32x16_bf16(kf3, qf[qs][3], z, 0, 0, 0);
                #pragma unroll
                for (int r = 0; r < 16; ++r) z[r] = __builtin_amdgcn_exp2f(z[r]);
                lsum[qs] += (((z[0]+z[1])+(z[2]+z[3])) + ((z[4]+z[5])+(z[6]+z[7])))
                          + (((z[8]+z[9])+(z[10]+z[11])) + ((z[12]+z[13])+(z[14]+z[15])));
                uint32_t x0 = cvtpk_bf16(z[0],  z[1]),  y0 = cvtpk_bf16(z[4],  z[5]);
                uint32_t x1 = cvtpk_bf16(z[2],  z[3]),  y1 = cvtpk_bf16(z[6],  z[7]);
                uint32_t x2 = cvtpk_bf16(z[8],  z[9]),  y2 = cvtpk_bf16(z[12], z[13]);
                uint32_t x3 = cvtpk_bf16(z[10], z[11]), y3 = cvtpk_bf16(z[14], z[15]);
                asm("v_permlane32_swap_b32 %0, %1" : "+v"(x0), "+v"(y0));
                asm("v_permlane32_swap_b32 %0, %1" : "+v"(x1), "+v"(y1));
                asm("v_permlane32_swap_b32 %0, %1" : "+v"(x2), "+v"(y2));
                asm("v_permlane32_swap_b32 %0, %1" : "+v"(x3), "+v"(y3));
                u32x4 t0 = {x0, x1, y0, y1};
                u32x4 t1 = {x2, x3, y2, y3};
                bf16x8 pa0 = __builtin_bit_cast(bf16x8, t0);
                bf16x8 pa1 = __builtin_bit_cast(bf16x8, t1);
                oacc[qs][0] = __builtin_amdgcn_mfma_f32_32x32x16_bf16(pa0, vf00, oacc[qs][0], 0, 0, 0);
                oacc[qs][1] = __builtin_amdgcn_mfma_f32_32x32x16_bf16(pa0, vf01, oacc[qs][1], 0, 0, 0);
                oacc[qs][0] = __builtin_amdgcn_mfma_f32_32x32x16_bf16(pa1, vf10, oacc[qs][0], 0, 0, 0);
                oacc[qs][1] = __builtin_amdgcn_mfma_f32_32x32x16_bf16(pa1, vf11, oacc[qs][1], 0, 0, 0);
            }
        }
        if (pfe) {
            short* Kn = (short*)Klds[cur ^ 1];
            short* Vn = (short*)Vlds[cur ^ 1];
            *(bf16x8*)&Kn[sr * 72 + sc]     = kr0;
            *(bf16x8*)&Kn[sr * 72 + sc + 8] = kr1;
            *(bf16x8*)&Vn[sr * 72 + sc]     = vr0;
            *(bf16x8*)&Vn[sr * 72 + sc + 8] = vr1;
        }
        __syncthreads();
    }

    #pragma unroll
    for (int qs = 0; qs < 2; ++qs) lsum[qs] += __shfl_xor(lsum[qs], 32);

    const long rowg = (long)b * T_SEQ + qt * 256 + wave * 64;
    if (outdirect) {
        if (lhi == 0) { Lred[wave][0][l31] = lsum[0]; Lred[wave][1][l31] = lsum[1]; }
        __syncthreads();
        float* ob = outdirect + rowg * HS;
        #pragma unroll
        for (int qs = 0; qs < 2; ++qs)
            #pragma unroll
            for (int ht = 0; ht < 2; ++ht)
                #pragma unroll
                for (int r = 0; r < 16; ++r) {
                    const int row = (r & 3) + 8 * (r >> 2) + 4 * lhi;
                    ob[(long)(qs * 32 + row) * HS + ht * 32 + l31] =
                        oacc[qs][ht][r] / Lred[wave][qs][row];
                }
    } else {
        float* op = Op + ((long)s * 32768 + rowg) * HS;
        #pragma unroll
        for (int qs = 0; qs < 2; ++qs)
            #pragma unroll
            for (int ht = 0; ht < 2; ++ht)
                #pragma unroll
                for (int r = 0; r < 16; ++r) {
                    const int row = (r & 3) + 8 * (r >> 2) + 4 * lhi;
                    op[(qs * 32 + row) * HS + ht * 32 + l31] = oacc[qs][ht][r];
                }
        if (lhi == 0) {
            lp[(long)s * 32768 + rowg + l31]      = lsum[0];
            lp[(long)s * 32768 + rowg + 32 + l31] = lsum[1];
        }
    }
}

// ---------------- combine partials: out = sum_s O_s / sum_s l_s ----------------
__global__ __launch_bounds__(256) void combine(const float4* __restrict__ Op,
        const float* __restrict__ lp, float4* __restrict__ out, const int ks) {
    const int idx = blockIdx.x * 256 + threadIdx.x;
    const int row = idx >> 4, h4 = idx & 15;
    float ox = 0.f, oy = 0.f, oz = 0.f, ow = 0.f, l = 0.f;
    for (int s = 0; s < ks; ++s) {
        float4 t = Op[(long)(s * 32768 + row) * 16 + h4];
        ox += t.x; oy += t.y; oz += t.z; ow += t.w;
        l += lp[s * 32768 + row];
    }
    const float inv = 1.0f / l;
    float4 o; o.x = ox * inv; o.y = oy * inv; o.z = oz * inv; o.w = ow * inv;
    out[(long)row * 16 + h4] = o;
}

extern "C" void kernel_launch(void* const* d_in, const int* in_sizes, int n_in,
                              void* d_out, int out_size, void* d_ws, size_t ws_size,
                              hipStream_t stream) {
    const float* x  = (const float*)d_in[0];
    const float* Wq = (const float*)d_in[1];
    const float* bq = (const float*)d_in[2];
    const float* Wk = (const float*)d_in[3];
    const float* bk = (const float*)d_in[4];
    const float* Wv = (const float*)d_in[5];
    const float* bv = (const float*)d_in[6];

    char* ws = (char*)d_ws;
    short* qo  = (short*)(ws);                     // 4 MB
    short* ko  = (short*)(ws + (4u << 20));        // 4 MB
    short* vto = (short*)(ws + (8u << 20));        // 4 MB  [b][h][t]
    short* wtf = (short*)(ws + (12u << 20));       // 288 KB
    const size_t opOff = 12582912u + 294912u;      // 12877824, 16B aligned
    float* Op = (float*)(ws + opOff);

    const size_t per_s = 8388608u + 131072u;       // O partial + l partial per split
    int ks = (ws_size >= opOff + 4 * per_s) ? 4
           : (ws_size >= opOff + 2 * per_s) ? 2 : 1;
    float* lp = (float*)(ws + opOff + (size_t)ks * 8388608u);

    prep_wt<<<288, 256, 0, stream>>>(Wq, Wk, Wv, wtf);
    qkv_proj<<<1024, 256, 0, stream>>>(x, bq, bk, bv, wtf, qo, ko, vto);
    attn<<<128 * ks, 256, 0, stream>>>(qo, ko, vto, Op, lp, ks,
                                       ks == 1 ? (float*)d_out : nullptr);
    if (ks > 1)
        combine<<<2048, 256, 0, stream>>>((const float4*)Op, lp, (float4*)d_out, ks);
}